// Round 17
// baseline (130.731 us; speedup 1.0000x reference)
//
#include <hip/hip_runtime.h>
#include <stdint.h>

#define K_DIM 1024
#define N_DIM 1024
#define BM 128
#define BN 128
#define BK 32
#define NT (K_DIM / BK)        // 32 K-tiles
#define AU32 (BM * 16)         // A unit: 128 rows x 16 u32 = 8 KB
#define NRING 3                // 24 KB LDS total

#define AS1 __attribute__((address_space(1)))
#define AS3 __attribute__((address_space(3)))

typedef __attribute__((ext_vector_type(4))) float f32x4;
typedef __attribute__((ext_vector_type(8))) short bf16x8;
typedef __attribute__((ext_vector_type(4))) uint32_t u32x4;

// round-half-up to bf16, pack two: low 16 = a, high 16 = b
__device__ __forceinline__ uint32_t pack_bf16(float a, float b) {
  uint32_t ua = __builtin_bit_cast(uint32_t, a) + 0x8000u;
  uint32_t ub = __builtin_bit_cast(uint32_t, b) + 0x8000u;
  return __builtin_amdgcn_perm(ub, ua, 0x07060302u);
}

__device__ __forceinline__ float wbin1(float v, float kkv, float aav) {
  float t = v * kkv;
  t = fminf(fmaxf(t, -1.0f), 1.0f);
  return t * aav;
}

// ---- kernel 1: w_bin -> wb in FRAGMENT-MAJOR layout --------------------
// wb[u32x4 index g], g = (c16*32 + kt)*64 + l:
//   lane l of fragment (c16, kt) holds B[col = c16*16 + (l&15)]
//                                      [k = kt*32 + (l>>4)*8 .. +8]  (8 bf16)
// GEMM B-operand load = ONE coalesced global_load_dwordx4 per fragment.
__global__ __launch_bounds__(256) void wconvf(const float* __restrict__ w,
                                              const float* __restrict__ kkp,
                                              const float* __restrict__ aap,
                                              uint32_t* __restrict__ wb) {
  const float kkv = kkp[0];
  const float aav = aap[0];
  const int g = blockIdx.x * 256 + threadIdx.x;  // 0 .. 131071
  const int l = g & 63;
  const int kt = (g >> 6) & 31;
  const int c16 = g >> 11;
  const int c = c16 * 16 + (l & 15);
  const int k = kt * 32 + (l >> 4) * 8;
  const f32x4* src = (const f32x4*)(w + (size_t)c * K_DIM + k);
  f32x4 v0 = src[0], v1 = src[1];
  u32x4 pk = {pack_bf16(wbin1(v0[0], kkv, aav), wbin1(v0[1], kkv, aav)),
              pack_bf16(wbin1(v0[2], kkv, aav), wbin1(v0[3], kkv, aav)),
              pack_bf16(wbin1(v1[0], kkv, aav), wbin1(v1[1], kkv, aav)),
              pack_bf16(wbin1(v1[2], kkv, aav), wbin1(v1[3], kkv, aav))};
  ((u32x4*)wb)[g] = pk;
}

// ---- kernel 2: B-from-global fused-A free-run GEMM ---------------------
// 128x128 tile, 256 thr = 4 waves (2x2), wave 64x64 (acc 64 VGPR), BK=32.
// B: direct global->reg from fragment-major wb (4 coalesced dwordx4 /wave
//    /tile), double-buffered in named sets BX/BY — NO LDS for B.
// A: LDS ring-3 of 8 KB units (24 KB total), fused fp32->bf16 convert,
//    2-tile cover: A(t+3) loaded at tile t (sets AX/AY), A(t+2) packed
//    mid-tile into unit (t+2)%3. Barrier needs only lgkmcnt(0) — no LDS
//    DMA exists, vmem flows freely across barriers.
// Per-wave vmem FIFO entering tile t: [B(t) 4, A(t+2) 2]; tile t issues
// B(t+1) 4 then A(t+3) 2; pre-MFMA vmcnt(8) retires B(t); mid vmcnt(6)
// retires A(t+2). Tail: 6/4, 4, 0. Manual waits are perf-shaping; the
// correctness chain is compiler auto-waitcnt (reg deps) + lgkm0+barrier.
// A-LDS swizzle both sides: phys_slot = slot ^ ((row>>1)&3), row = 16 u32.
__global__ __launch_bounds__(256, 3) void binlin_bg(
    const float* __restrict__ x, const uint32_t* __restrict__ wb,
    const float* __restrict__ bias, float* __restrict__ out) {
  __shared__ uint32_t lds[NRING * AU32];  // 24 KB

  const int tid = threadIdx.x;

  // bijective XCD swizzle (grid=2048): 8 n-blocks of an m-panel -> same L2
  const int per = gridDim.x >> 3;
  const int logical = (blockIdx.x & 7) * per + (blockIdx.x >> 3);
  const int mIdx = logical >> 3;  // N_DIM/BN = 8
  const int nIdx = logical & 7;
  const int row0 = mIdx * BM;
  const int col0 = nIdx * BN;

  const int w4 = tid >> 6;  // wave 0..3
  const int lane = tid & 63;
  const int wr = w4 >> 1;   // 0..1 (m half)
  const int wc = w4 & 1;    // 0..1 (n half)
  const int cl = lane & 15;
  const int kg = lane >> 4;

  // ---- A staging: thread -> row r = tid>>1 (0..127), half h = tid&1 ----
  const int r = tid >> 1;
  const int h = tid & 1;
  const float* ga = x + (size_t)(row0 + r) * K_DIM + h * 16;
  const int sw = (r >> 1) & 3;
  const int awidx0 = r * 16 + (((h * 2) ^ sw) * 4);
  const int awidx1 = r * 16 + (((h * 2 + 1) ^ sw) * 4);

  // ---- B fragment base: wave covers col16 groups cb16 .. cb16+3 ----
  const int cb16 = (col0 >> 4) + wc * 4;
  const uint32_t* gbf = wb + (size_t)lane * 4;  // + ((c16*32+kt)*64)*4

  f32x4 acc[4][4] = {};
  bf16x8 af[4];
  bf16x8 BX0, BX1, BX2, BX3, BY0, BY1, BY2, BY3;  // B frag sets
  f32x4 XA0, XA1, XA2, XA3, YA0, YA1, YA2, YA3;   // A fp32 sets (16 f ea)

#define LOAD_B4(kt, B0, B1, B2, B3)                                        \
  do {                                                                     \
    B0 = *(const bf16x8*)(gbf + ((size_t)((cb16 + 0) * 32 + (kt)) << 8));  \
    B1 = *(const bf16x8*)(gbf + ((size_t)((cb16 + 1) * 32 + (kt)) << 8));  \
    B2 = *(const bf16x8*)(gbf + ((size_t)((cb16 + 2) * 32 + (kt)) << 8));  \
    B3 = *(const bf16x8*)(gbf + ((size_t)((cb16 + 3) * 32 + (kt)) << 8));  \
  } while (0)

#define LOAD_A4(kt, R0, R1, R2, R3)                            \
  do {                                                         \
    const f32x4* pa = (const f32x4*)(ga + (size_t)(kt) * 32);  \
    R0 = pa[0]; R1 = pa[1]; R2 = pa[2]; R3 = pa[3];            \
  } while (0)

#define PACK_A(SD, R0, R1, R2, R3)                                        \
  do {                                                                    \
    u32x4 q0 = {pack_bf16(R0[0], R0[1]), pack_bf16(R0[2], R0[3]),         \
                pack_bf16(R1[0], R1[1]), pack_bf16(R1[2], R1[3])};        \
    u32x4 q1 = {pack_bf16(R2[0], R2[1]), pack_bf16(R2[2], R2[3]),         \
                pack_bf16(R3[0], R3[1]), pack_bf16(R3[2], R3[3])};        \
    *(u32x4*)((SD) + awidx0) = q0;                                        \
    *(u32x4*)((SD) + awidx1) = q1;                                        \
  } while (0)

#define READ_AF(AB)                                                          \
  _Pragma("unroll") for (int m = 0; m < 4; ++m) {                            \
    int rr = wr * 64 + m * 16 + cl;                                          \
    af[m] =                                                                  \
        *(const bf16x8*)((AB) + rr * 16 + ((kg ^ ((rr >> 1) & 3)) * 4));     \
  }

#define MFMA2(N0, BF0, N1, BF1)                                              \
  __builtin_amdgcn_s_setprio(1);                                             \
  _Pragma("unroll") for (int m = 0; m < 4; ++m) {                            \
    acc[m][N0] = __builtin_amdgcn_mfma_f32_16x16x32_bf16(af[m], BF0,         \
                                                         acc[m][N0], 0, 0, 0);\
    acc[m][N1] = __builtin_amdgcn_mfma_f32_16x16x32_bf16(af[m], BF1,         \
                                                         acc[m][N1], 0, 0, 0);\
  }                                                                          \
  __builtin_amdgcn_s_setprio(0);

  // TILE: compute unit t%3 with B-set U*, stage B(t+1)->L*, A(t+3)->AL*,
  // pack A(t+2) (AP*) into unit (t+2)%3.
#define TILE(T, DOB, DOA, PRE, MID, DOPACK, DOBAR, U0, U1, U2, U3, L0, L1, \
             L2, L3, AP0, AP1, AP2, AP3, AL0, AL1, AL2, AL3)               \
  do {                                                                     \
    const int t_ = (T);                                                    \
    const uint32_t* AB = &lds[(t_ % 3) * AU32];                            \
    uint32_t* SD = &lds[((t_ + 2) % 3) * AU32];                            \
    if (DOB) LOAD_B4(t_ + 1, L0, L1, L2, L3);                              \
    if (DOA) LOAD_A4(t_ + 3, AL0, AL1, AL2, AL3);                          \
    READ_AF(AB);                                                           \
    asm volatile("s_waitcnt vmcnt(" #PRE ")" ::: "memory");                \
    MFMA2(0, U0, 1, U1);                                                   \
    if (DOPACK) {                                                          \
      asm volatile("s_waitcnt vmcnt(" #MID ")" ::: "memory");              \
      PACK_A(SD, AP0, AP1, AP2, AP3);                                      \
    }                                                                      \
    MFMA2(2, U2, 3, U3);                                                   \
    if (DOBAR) {                                                           \
      asm volatile("s_waitcnt lgkmcnt(0)" ::: "memory");                   \
      __builtin_amdgcn_s_barrier();                                        \
    }                                                                      \
  } while (0)

  // ---- prologue: FIFO target entering tile 0 = [B(0) 4, A(2) 2] ----
  {
    f32x4 T00, T01, T02, T03, T10, T11, T12, T13;
    LOAD_A4(0, T00, T01, T02, T03);
    LOAD_A4(1, T10, T11, T12, T13);
    LOAD_B4(0, BX0, BX1, BX2, BX3);
    LOAD_A4(2, XA0, XA1, XA2, XA3);
    PACK_A(&lds[0], T00, T01, T02, T03);      // auto-waits A(0)
    PACK_A(&lds[AU32], T10, T11, T12, T13);   // auto-waits A(1)
    asm volatile("s_waitcnt lgkmcnt(0)" ::: "memory");
    __builtin_amdgcn_s_barrier();
  }

  // steady tiles 0..27, unroll-2:
  // even t: use BX, load B->BY; pack XA (=A(t+2)), load YA (<-A(t+3))
  for (int t2 = 0; t2 < 28; t2 += 2) {
    TILE(t2, 1, 1, 8, 6, 1, 1, BX0, BX1, BX2, BX3, BY0, BY1, BY2, BY3,
         XA0, XA1, XA2, XA3, YA0, YA1, YA2, YA3);
    TILE(t2 + 1, 1, 1, 8, 6, 1, 1, BY0, BY1, BY2, BY3, BX0, BX1, BX2, BX3,
         YA0, YA1, YA2, YA3, XA0, XA1, XA2, XA3);
  }
  // t=28 (even, steady): B(29)->BY, A(31)->YA, pack XA=A(30)
  TILE(28, 1, 1, 8, 6, 1, 1, BX0, BX1, BX2, BX3, BY0, BY1, BY2, BY3,
       XA0, XA1, XA2, XA3, YA0, YA1, YA2, YA3);
  // t=29 (odd): B(30)->BX, no A; entering 6, +4 -> pre 6, mid 4, pack YA=A(31)
  TILE(29, 1, 0, 6, 4, 1, 1, BY0, BY1, BY2, BY3, BX0, BX1, BX2, BX3,
       YA0, YA1, YA2, YA3, XA0, XA1, XA2, XA3);
  // t=30 (even): B(31)->BY, no A; entering 4, +4 -> pre 4, no pack
  TILE(30, 1, 0, 4, 0, 0, 1, BX0, BX1, BX2, BX3, BY0, BY1, BY2, BY3,
       XA0, XA1, XA2, XA3, YA0, YA1, YA2, YA3);
  // t=31 (odd): nothing to issue; pre 0, no pack, no barrier
  TILE(31, 0, 0, 0, 0, 0, 0, BY0, BY1, BY2, BY3, BX0, BX1, BX2, BX3,
       YA0, YA1, YA2, YA3, XA0, XA1, XA2, XA3);

  // ---- epilogue: bias + fp32 store ----
#pragma unroll
  for (int n = 0; n < 4; ++n) {
    int col = col0 + wc * 64 + n * 16 + cl;
    float bv = bias[col];
#pragma unroll
    for (int m = 0; m < 4; ++m) {
      int rowb = row0 + wr * 64 + m * 16 + kg * 4;
#pragma unroll
      for (int i = 0; i < 4; ++i) {
        out[(size_t)(rowb + i) * N_DIM + col] = acc[m][n][i] + bv;
      }
    }
  }
#undef LOAD_B4
#undef LOAD_A4
#undef PACK_A
#undef READ_AF
#undef MFMA2
#undef TILE
}

extern "C" void kernel_launch(void* const* d_in, const int* in_sizes, int n_in,
                              void* d_out, int out_size, void* d_ws, size_t ws_size,
                              hipStream_t stream) {
  const float* x = (const float*)d_in[0];
  const float* w = (const float*)d_in[1];
  const float* bias = (const float*)d_in[2];
  const float* kk = (const float*)d_in[3];
  const float* aa = (const float*)d_in[4];
  float* out = (float*)d_out;

  uint32_t* wb = (uint32_t*)d_ws;  // 2 MB fragment-major bf16 w_bin
  wconvf<<<(N_DIM / 16) * NT * 64 / 256, 256, 0, stream>>>(w, kk, aa, wb);

  const int M = in_sizes[0] / K_DIM;         // 32768
  const int grid = (M / BM) * (N_DIM / BN);  // 256 * 8 = 2048
  binlin_bg<<<grid, 256, 0, stream>>>(x, wb, bias, out);
}

// Round 18
// 112.300 us; speedup vs baseline: 1.1641x; 1.1641x over previous
//
#include <hip/hip_runtime.h>
#include <stdint.h>

#define K_DIM 1024
#define N_DIM 1024
#define BM 128
#define BN 256
#define BK 32
#define NT (K_DIM / BK)             // 32 K-tiles
#define AOFF_U32 (BM * 16)          // A region: 128 rows x 16 u32
#define UNIT_U32 ((BM + BN) * 16)   // 24 KB per ring unit
#define NRING 3                     // 72 KB -> 2 blocks/CU

#define AS1 __attribute__((address_space(1)))
#define AS3 __attribute__((address_space(3)))

typedef __attribute__((ext_vector_type(4))) float f32x4;
typedef __attribute__((ext_vector_type(8))) short bf16x8;
typedef __attribute__((ext_vector_type(4))) uint32_t u32x4;

// round-half-up to bf16, pack two: low 16 = a, high 16 = b
__device__ __forceinline__ uint32_t pack_bf16(float a, float b) {
  uint32_t ua = __builtin_bit_cast(uint32_t, a) + 0x8000u;
  uint32_t ub = __builtin_bit_cast(uint32_t, b) + 0x8000u;
  return __builtin_amdgcn_perm(ub, ua, 0x07060302u);
}

__device__ __forceinline__ float wbin1(float v, float kkv, float aav) {
  float t = v * kkv;
  t = fminf(fmaxf(t, -1.0f), 1.0f);
  return t * aav;
}

// ---------------- kernel 1: w_bin = bf16(aa*clamp(kk*w,-1,1)) into ws ------
__global__ __launch_bounds__(256) void wconv(const float* __restrict__ w,
                                             const float* __restrict__ kkp,
                                             const float* __restrict__ aap,
                                             uint32_t* __restrict__ wb) {
  const float kkv = kkp[0];
  const float aav = aap[0];
  const int g = blockIdx.x * 256 + threadIdx.x;  // 16 floats per thread
  const f32x4* src = (const f32x4*)(w + (size_t)g * 16);
  f32x4 v0 = src[0], v1 = src[1], v2 = src[2], v3 = src[3];
  uint32_t p[8];
#pragma unroll
  for (int i = 0; i < 4; ++i) {
    f32x4 v = i == 0 ? v0 : (i == 1 ? v1 : (i == 2 ? v2 : v3));
    p[2 * i] = pack_bf16(wbin1(v[0], kkv, aav), wbin1(v[1], kkv, aav));
    p[2 * i + 1] = pack_bf16(wbin1(v[2], kkv, aav), wbin1(v[3], kkv, aav));
  }
  u32x4* dst = (u32x4*)(wb + (size_t)g * 8);
  dst[0] = u32x4{p[0], p[1], p[2], p[3]};
  dst[1] = u32x4{p[4], p[5], p[6], p[7]};
}

// ---------------- kernel 2: fused-convert ring-3, deep-A free-run GEMM -----
// R16 champion (tile 128x256, 512 thr = 8 waves 2x4, wave 64x64, BK=32,
// ring-3 24KB units = 72 KB -> 2 blocks/CU, deep-A 2-tile cover, free-run
// body, 1 barrier/tile) with ONE change: the mid-tile vmcnt(4)+PACK_A moves
// BEFORE MFMA cluster 0 (right after the ds_read issues). FIFO math is
// unchanged (entering [B(t+1)2, A(t+2)2]; +4 issued; vmcnt(4) retires
// exactly B(t+1)+A(t+2)); the pack's ds_write drains under the MFMA
// clusters; clusters now run back-to-back (only READ_BF(1) between).
// Swizzle both sides: phys_slot = slot ^ ((row>>1)&3), row = 16 u32.
__global__ __launch_bounds__(512, 4) void binlin_fused3b(
    const float* __restrict__ x, const uint32_t* __restrict__ wb,
    const float* __restrict__ bias, float* __restrict__ out) {
  __shared__ uint32_t lds[NRING * UNIT_U32];  // 72 KB

  const int tid = threadIdx.x;

  // bijective XCD swizzle (grid=1024): 4 n-blocks of an m-panel -> same L2
  const int per = gridDim.x >> 3;
  const int logical = (blockIdx.x & 7) * per + (blockIdx.x >> 3);
  const int mIdx = logical >> 2;  // N_DIM/BN = 4
  const int nIdx = logical & 3;
  const int row0 = mIdx * BM;
  const int col0 = nIdx * BN;

  const int w8 = tid >> 6;
  const int lane = tid & 63;

  // ---- A reg-staging: wave w8 covers rows [w8*16, w8*16+16) ----
  const int arow = w8 * 16 + (lane >> 2);       // local row 0..127
  const int aslot = lane & 3;                   // logical 16B k-slot
  const float* ga = x + (size_t)(row0 + arow) * K_DIM + aslot * 8;
  const int awidx = arow * 16 + ((aslot ^ ((arow >> 1) & 3)) * 4);

  // ---- B staging via global_load_lds: wave w8 rows [w8*32, +32), 2 ops ----
  const int rl = lane >> 2;
  const int sl = (lane & 3) ^ ((lane >> 3) & 3);  // pre-swizzled source slot
  const uint32_t* gb_base =
      wb + (size_t)(col0 + w8 * 32 + rl) * (K_DIM / 2) + sl * 4;

  // ---- compute indices (wave 64x64) ----
  const int wr = w8 >> 2;   // 0..1
  const int wc = w8 & 3;    // 0..3
  const int cl = lane & 15;
  const int kg = lane >> 4;

  f32x4 acc[4][4] = {};
  bf16x8 af[4], bfr[2];
  f32x4 XA0, XA1, YA0, YA1;  // two A fp32 sets in flight (8 floats each)

#define STAGE_B1(kt, SD, c)                                               \
  __builtin_amdgcn_global_load_lds(                                       \
      (const AS1 uint32_t*)(gb_base + (size_t)((c)*16) * (K_DIM / 2) +    \
                            (kt)*16),                                     \
      (AS3 uint32_t*)((SD) + AOFF_U32 + (w8 * 32 + (c)*16) * 16), 16, 0, 0)

#define LOAD_A2(kt, R0, R1)                                   \
  do {                                                        \
    const f32x4* pa = (const f32x4*)(ga + (size_t)(kt) * 32); \
    R0 = pa[0];                                               \
    R1 = pa[1];                                               \
  } while (0)

#define PACK_A(SD, R0, R1)                                                \
  do {                                                                    \
    u32x4 pk = {pack_bf16(R0[0], R0[1]), pack_bf16(R0[2], R0[3]),         \
                pack_bf16(R1[0], R1[1]), pack_bf16(R1[2], R1[3])};        \
    *(u32x4*)((SD) + awidx) = pk;                                         \
  } while (0)

#define READ_AF(AB)                                                            \
  _Pragma("unroll") for (int m = 0; m < 4; ++m) {                              \
    int rr = wr * 64 + m * 16 + cl;                                            \
    af[m] =                                                                    \
        *(const bf16x8*)((AB) + rr * 16 + ((kg ^ ((rr >> 1) & 3)) * 4));       \
  }

#define READ_BF(BB, NH)                                                        \
  _Pragma("unroll") for (int n = 0; n < 2; ++n) {                              \
    int rr = wc * 64 + ((NH)*2 + n) * 16 + cl;                                 \
    bfr[n] =                                                                   \
        *(const bf16x8*)((BB) + rr * 16 + ((kg ^ ((rr >> 1) & 3)) * 4));       \
  }

#define MFMA_CL(NH)                                                            \
  __builtin_amdgcn_s_setprio(1);                                               \
  _Pragma("unroll") for (int m = 0; m < 4; ++m)                                \
  _Pragma("unroll") for (int n = 0; n < 2; ++n)                                \
  acc[m][(NH)*2 + n] = __builtin_amdgcn_mfma_f32_16x16x32_bf16(                \
      af[m], bfr[n], acc[m][(NH)*2 + n], 0, 0, 0);                             \
  __builtin_amdgcn_s_setprio(0);

  // TILE(t): issue B(t+2)->su, A(t+3)->L; ds_reads; EARLY vmcnt(MIDN)+pack
  // A(t+2) (set P) -> su; then both MFMA clusters; boundary lgkm+barrier.
#define TILE(DOB, DOA, MIDN, DOPACK, DOBAR, P0, P1, L0, L1, TB, TA)       \
  do {                                                                    \
    const uint32_t* AB = &lds[cu * UNIT_U32];                             \
    const uint32_t* BB = AB + AOFF_U32;                                   \
    uint32_t* SD = &lds[su * UNIT_U32];                                   \
    if (DOB) {                                                            \
      STAGE_B1((TB), SD, 0);                                              \
      STAGE_B1((TB), SD, 1);                                              \
    }                                                                     \
    if (DOA) LOAD_A2((TA), L0, L1);                                       \
    READ_AF(AB);                                                          \
    READ_BF(BB, 0);                                                       \
    asm volatile("s_waitcnt vmcnt(" #MIDN ")" ::: "memory");              \
    if (DOPACK) PACK_A(SD, P0, P1);                                       \
    MFMA_CL(0);                                                           \
    READ_BF(BB, 1);                                                       \
    MFMA_CL(1);                                                           \
    if (DOBAR) {                                                          \
      asm volatile("s_waitcnt lgkmcnt(0)" ::: "memory");                  \
      __builtin_amdgcn_s_barrier();                                       \
    }                                                                     \
    cu = (cu == NRING - 1) ? 0 : cu + 1;                                  \
    su = (su == NRING - 1) ? 0 : su + 1;                                  \
  } while (0)

  // ---- prologue ----
  // FIFO target entering tile 0: [B(1) 2, A(2) 2].
  {
    f32x4 T00, T01, T10, T11;
    LOAD_A2(0, T00, T01);
    LOAD_A2(1, T10, T11);
    STAGE_B1(0, &lds[0], 0);
    STAGE_B1(0, &lds[0], 1);
    STAGE_B1(1, &lds[UNIT_U32], 0);
    STAGE_B1(1, &lds[UNIT_U32], 1);
    PACK_A(&lds[0], T00, T01);           // auto-waits A(0)
    PACK_A(&lds[UNIT_U32], T10, T11);    // auto-waits A(1)
    LOAD_A2(2, XA0, XA1);                // A(2) -> X, stays in flight
    asm volatile("s_waitcnt vmcnt(4)" ::: "memory");  // retire B(0); keep B(1)+A(2)
    asm volatile("s_waitcnt lgkmcnt(0)" ::: "memory");
    __builtin_amdgcn_s_barrier();
  }

  int cu = 0, su = 2;
  // steady tiles t = 0..27 (even count), unroll-2 for A-set parity:
  // even t: pack X (=A(t+2)), load Y (<-A(t+3)); odd t: reverse.
  for (int t2 = 0; t2 < 28; t2 += 2) {
    TILE(1, 1, 4, 1, 1, XA0, XA1, YA0, YA1, t2 + 2, t2 + 3);
    TILE(1, 1, 4, 1, 1, YA0, YA1, XA0, XA1, t2 + 3, t2 + 4);
  }
  // t=28 (even, steady): B(30), A(31)->Y, pack X=A(30)
  TILE(1, 1, 4, 1, 1, XA0, XA1, YA0, YA1, 30, 31);
  // t=29 (odd): B(31), no A-load, vmcnt(2), pack Y=A(31)
  TILE(1, 0, 2, 1, 1, YA0, YA1, XA0, XA1, 31, 0);
  // t=30: nothing to issue, vmcnt(0), no pack
  TILE(0, 0, 0, 0, 1, XA0, XA1, YA0, YA1, 0, 0);
  // t=31: compute only
  TILE(0, 0, 0, 0, 0, XA0, XA1, YA0, YA1, 0, 0);

  // ---- epilogue: bias + fp32 store ----
#pragma unroll
  for (int n = 0; n < 4; ++n) {
    int col = col0 + wc * 64 + n * 16 + cl;
    float bv = bias[col];
#pragma unroll
    for (int m = 0; m < 4; ++m) {
      int rowb = row0 + wr * 64 + m * 16 + kg * 4;
#pragma unroll
      for (int i = 0; i < 4; ++i) {
        out[(size_t)(rowb + i) * N_DIM + col] = acc[m][n][i] + bv;
      }
    }
  }
#undef STAGE_B1
#undef LOAD_A2
#undef PACK_A
#undef READ_AF
#undef READ_BF
#undef MFMA_CL
#undef TILE
}

extern "C" void kernel_launch(void* const* d_in, const int* in_sizes, int n_in,
                              void* d_out, int out_size, void* d_ws, size_t ws_size,
                              hipStream_t stream) {
  const float* x = (const float*)d_in[0];
  const float* w = (const float*)d_in[1];
  const float* bias = (const float*)d_in[2];
  const float* kk = (const float*)d_in[3];
  const float* aa = (const float*)d_in[4];
  float* out = (float*)d_out;

  uint32_t* wb = (uint32_t*)d_ws;  // 2 MB bf16 w_bin
  wconv<<<(N_DIM * K_DIM) / (256 * 16), 256, 0, stream>>>(w, kk, aa, wb);

  const int M = in_sizes[0] / K_DIM;         // 32768
  const int grid = (M / BM) * (N_DIM / BN);  // 256 * 4 = 1024
  binlin_fused3b<<<grid, 512, 0, stream>>>(x, wb, bias, out);
}

// Round 19
// 109.398 us; speedup vs baseline: 1.1950x; 1.0265x over previous
//
#include <hip/hip_runtime.h>
#include <stdint.h>

#define K_DIM 1024
#define N_DIM 1024
#define BM 128
#define BN 256
#define BK 32
#define NT (K_DIM / BK)             // 32 K-tiles
#define AOFF_U32 (BM * 16)          // A region: 128 rows x 16 u32
#define UNIT_U32 ((BM + BN) * 16)   // 24 KB per ring unit
#define NRING 3                     // 72 KB -> 2 blocks/CU

#define AS1 __attribute__((address_space(1)))
#define AS3 __attribute__((address_space(3)))

typedef __attribute__((ext_vector_type(4))) float f32x4;
typedef __attribute__((ext_vector_type(16))) float f32x16;
typedef __attribute__((ext_vector_type(8))) short bf16x8;
typedef __attribute__((ext_vector_type(4))) uint32_t u32x4;

// round-half-up to bf16, pack two: low 16 = a, high 16 = b
__device__ __forceinline__ uint32_t pack_bf16(float a, float b) {
  uint32_t ua = __builtin_bit_cast(uint32_t, a) + 0x8000u;
  uint32_t ub = __builtin_bit_cast(uint32_t, b) + 0x8000u;
  return __builtin_amdgcn_perm(ub, ua, 0x07060302u);
}

__device__ __forceinline__ float wbin1(float v, float kkv, float aav) {
  float t = v * kkv;
  t = fminf(fmaxf(t, -1.0f), 1.0f);
  return t * aav;
}

// ---------------- kernel 1: w_bin = bf16(aa*clamp(kk*w,-1,1)) into ws ------
__global__ __launch_bounds__(256) void wconv(const float* __restrict__ w,
                                             const float* __restrict__ kkp,
                                             const float* __restrict__ aap,
                                             uint32_t* __restrict__ wb) {
  const float kkv = kkp[0];
  const float aav = aap[0];
  const int g = blockIdx.x * 256 + threadIdx.x;  // 16 floats per thread
  const f32x4* src = (const f32x4*)(w + (size_t)g * 16);
  f32x4 v0 = src[0], v1 = src[1], v2 = src[2], v3 = src[3];
  uint32_t p[8];
#pragma unroll
  for (int i = 0; i < 4; ++i) {
    f32x4 v = i == 0 ? v0 : (i == 1 ? v1 : (i == 2 ? v2 : v3));
    p[2 * i] = pack_bf16(wbin1(v[0], kkv, aav), wbin1(v[1], kkv, aav));
    p[2 * i + 1] = pack_bf16(wbin1(v[2], kkv, aav), wbin1(v[3], kkv, aav));
  }
  u32x4* dst = (u32x4*)(wb + (size_t)g * 8);
  dst[0] = u32x4{p[0], p[1], p[2], p[3]};
  dst[1] = u32x4{p[4], p[5], p[6], p[7]};
}

// ---------------- kernel 2: R16 structure, 32x32x16 MFMA -------------------
// R16 champion schedule verbatim (tile 128x256, 512 thr = 8 waves 2x4, wave
// 64x64, BK=32, ring-3 24KB units = 72 KB -> 2 blocks/CU, deep-A 2-tile
// cover, free-run body, 1 barrier/tile, mid-tile vmcnt(4)+PACK between MFMA
// clusters). ONLY change: compute uses v_mfma_f32_32x32x16_bf16 —
// wave 64x64 = 2x2 frags of 32x32, 2 k-steps/tile, 8 MFMA/tile (was 16),
// acc f32x16[2][2] (64 VGPR, unchanged), same LDS bytes read.
// Fragment maps (m74/m101 verified): A/B lane: row/col = lane&31,
// k = (lane>>5)*8..+8; C/D: col=lane&31, row=(reg&3)+8*(reg>>2)+4*(lane>>5).
// Swizzle both sides: phys_slot = slot ^ ((row>>1)&3), row = 16 u32.
__global__ __launch_bounds__(512, 4) void binlin_fused3c(
    const float* __restrict__ x, const uint32_t* __restrict__ wb,
    const float* __restrict__ bias, float* __restrict__ out) {
  __shared__ uint32_t lds[NRING * UNIT_U32];  // 72 KB

  const int tid = threadIdx.x;

  // bijective XCD swizzle (grid=1024): 4 n-blocks of an m-panel -> same L2
  const int per = gridDim.x >> 3;
  const int logical = (blockIdx.x & 7) * per + (blockIdx.x >> 3);
  const int mIdx = logical >> 2;  // N_DIM/BN = 4
  const int nIdx = logical & 3;
  const int row0 = mIdx * BM;
  const int col0 = nIdx * BN;

  const int w8 = tid >> 6;
  const int lane = tid & 63;

  // ---- A reg-staging: wave w8 covers rows [w8*16, w8*16+16) ----
  const int arow = w8 * 16 + (lane >> 2);       // local row 0..127
  const int aslot = lane & 3;                   // logical 16B k-slot
  const float* ga = x + (size_t)(row0 + arow) * K_DIM + aslot * 8;
  const int awidx = arow * 16 + ((aslot ^ ((arow >> 1) & 3)) * 4);

  // ---- B staging via global_load_lds: wave w8 rows [w8*32, +32), 2 ops ----
  const int rl = lane >> 2;
  const int sl = (lane & 3) ^ ((lane >> 3) & 3);  // pre-swizzled source slot
  const uint32_t* gb_base =
      wb + (size_t)(col0 + w8 * 32 + rl) * (K_DIM / 2) + sl * 4;

  // ---- compute indices (wave 64x64, 32x32 frags) ----
  const int wr = w8 >> 2;     // 0..1
  const int wc = w8 & 3;      // 0..3
  const int l31 = lane & 31;  // frag row/col
  const int kh = lane >> 5;   // k-half (0..1) within 16-wide k-step

  f32x16 acc[2][2] = {};
  bf16x8 af[4], bfr[2];
  f32x4 XA0, XA1, YA0, YA1;  // two A fp32 sets in flight (8 floats each)

#define STAGE_B1(kt, SD, c)                                               \
  __builtin_amdgcn_global_load_lds(                                       \
      (const AS1 uint32_t*)(gb_base + (size_t)((c)*16) * (K_DIM / 2) +    \
                            (kt)*16),                                     \
      (AS3 uint32_t*)((SD) + AOFF_U32 + (w8 * 32 + (c)*16) * 16), 16, 0, 0)

#define LOAD_A2(kt, R0, R1)                                   \
  do {                                                        \
    const f32x4* pa = (const f32x4*)(ga + (size_t)(kt) * 32); \
    R0 = pa[0];                                               \
    R1 = pa[1];                                               \
  } while (0)

#define PACK_A(SD, R0, R1)                                                \
  do {                                                                    \
    u32x4 pk = {pack_bf16(R0[0], R0[1]), pack_bf16(R0[2], R0[3]),         \
                pack_bf16(R1[0], R1[1]), pack_bf16(R1[2], R1[3])};        \
    *(u32x4*)((SD) + awidx) = pk;                                         \
  } while (0)

  // af[mf*2+ks]: A frag, rows wr*64+mf*32+l31, k-slot ks*2+kh
#define READ_AF(AB)                                                            \
  _Pragma("unroll") for (int mf = 0; mf < 2; ++mf)                             \
  _Pragma("unroll") for (int ks = 0; ks < 2; ++ks) {                           \
    int rr = wr * 64 + mf * 32 + l31;                                          \
    int s2 = ks * 2 + kh;                                                      \
    af[mf * 2 + ks] =                                                          \
        *(const bf16x8*)((AB) + rr * 16 + ((s2 ^ ((rr >> 1) & 3)) * 4));       \
  }

  // bfr[ks]: B frag for n-frag NH, cols wc*64+NH*32+l31
#define READ_BF(BB, NH)                                                        \
  _Pragma("unroll") for (int ks = 0; ks < 2; ++ks) {                           \
    int rr = wc * 64 + (NH)*32 + l31;                                          \
    int s2 = ks * 2 + kh;                                                      \
    bfr[ks] =                                                                  \
        *(const bf16x8*)((BB) + rr * 16 + ((s2 ^ ((rr >> 1) & 3)) * 4));       \
  }

#define MFMA_CL(NH)                                                            \
  __builtin_amdgcn_s_setprio(1);                                               \
  _Pragma("unroll") for (int ks = 0; ks < 2; ++ks)                             \
  _Pragma("unroll") for (int mf = 0; mf < 2; ++mf)                             \
  acc[mf][NH] = __builtin_amdgcn_mfma_f32_32x32x16_bf16(                       \
      af[mf * 2 + ks], bfr[ks], acc[mf][NH], 0, 0, 0);                         \
  __builtin_amdgcn_s_setprio(0);

  // TILE(t): issue B(t+2)->su, A(t+3)->L; ds_reads; cluster 0; mid-tile
  // vmcnt(MIDN)+pack A(t+2) (set P) -> su; cluster 1; boundary lgkm+barrier.
#define TILE(DOB, DOA, MIDN, DOPACK, DOBAR, P0, P1, L0, L1, TB, TA)       \
  do {                                                                    \
    const uint32_t* AB = &lds[cu * UNIT_U32];                             \
    const uint32_t* BB = AB + AOFF_U32;                                   \
    uint32_t* SD = &lds[su * UNIT_U32];                                   \
    if (DOB) {                                                            \
      STAGE_B1((TB), SD, 0);                                              \
      STAGE_B1((TB), SD, 1);                                              \
    }                                                                     \
    if (DOA) LOAD_A2((TA), L0, L1);                                       \
    READ_AF(AB);                                                          \
    READ_BF(BB, 0);                                                       \
    MFMA_CL(0);                                                           \
    asm volatile("s_waitcnt vmcnt(" #MIDN ")" ::: "memory");              \
    if (DOPACK) PACK_A(SD, P0, P1);                                       \
    READ_BF(BB, 1);                                                       \
    MFMA_CL(1);                                                           \
    if (DOBAR) {                                                          \
      asm volatile("s_waitcnt lgkmcnt(0)" ::: "memory");                  \
      __builtin_amdgcn_s_barrier();                                       \
    }                                                                     \
    cu = (cu == NRING - 1) ? 0 : cu + 1;                                  \
    su = (su == NRING - 1) ? 0 : su + 1;                                  \
  } while (0)

  // ---- prologue ----
  // FIFO target entering tile 0: [B(1) 2, A(2) 2].
  {
    f32x4 T00, T01, T10, T11;
    LOAD_A2(0, T00, T01);
    LOAD_A2(1, T10, T11);
    STAGE_B1(0, &lds[0], 0);
    STAGE_B1(0, &lds[0], 1);
    STAGE_B1(1, &lds[UNIT_U32], 0);
    STAGE_B1(1, &lds[UNIT_U32], 1);
    PACK_A(&lds[0], T00, T01);           // auto-waits A(0)
    PACK_A(&lds[UNIT_U32], T10, T11);    // auto-waits A(1)
    LOAD_A2(2, XA0, XA1);                // A(2) -> X, stays in flight
    asm volatile("s_waitcnt vmcnt(4)" ::: "memory");  // retire B(0); keep B(1)+A(2)
    asm volatile("s_waitcnt lgkmcnt(0)" ::: "memory");
    __builtin_amdgcn_s_barrier();
  }

  int cu = 0, su = 2;
  // steady tiles t = 0..27 (even count), unroll-2 for A-set parity:
  // even t: pack X (=A(t+2)), load Y (<-A(t+3)); odd t: reverse.
  for (int t2 = 0; t2 < 28; t2 += 2) {
    TILE(1, 1, 4, 1, 1, XA0, XA1, YA0, YA1, t2 + 2, t2 + 3);
    TILE(1, 1, 4, 1, 1, YA0, YA1, XA0, XA1, t2 + 3, t2 + 4);
  }
  // t=28 (even, steady): B(30), A(31)->Y, pack X=A(30)
  TILE(1, 1, 4, 1, 1, XA0, XA1, YA0, YA1, 30, 31);
  // t=29 (odd): B(31), no A-load, vmcnt(2), pack Y=A(31)
  TILE(1, 0, 2, 1, 1, YA0, YA1, XA0, XA1, 31, 0);
  // t=30: nothing to issue, vmcnt(0), no pack
  TILE(0, 0, 0, 0, 1, XA0, XA1, YA0, YA1, 0, 0);
  // t=31: compute only
  TILE(0, 0, 0, 0, 0, XA0, XA1, YA0, YA1, 0, 0);

  // ---- epilogue: bias + fp32 store (32x32 C/D layout) ----
#pragma unroll
  for (int nf = 0; nf < 2; ++nf) {
    int col = col0 + wc * 64 + nf * 32 + l31;
    float bv = bias[col];
#pragma unroll
    for (int mf = 0; mf < 2; ++mf) {
#pragma unroll
      for (int i = 0; i < 16; ++i) {
        int row = row0 + wr * 64 + mf * 32 + (i & 3) + 8 * (i >> 2) + 4 * kh;
        out[(size_t)row * N_DIM + col] = acc[mf][nf][i] + bv;
      }
    }
  }
#undef STAGE_B1
#undef LOAD_A2
#undef PACK_A
#undef READ_AF
#undef READ_BF
#undef MFMA_CL
#undef TILE
}

extern "C" void kernel_launch(void* const* d_in, const int* in_sizes, int n_in,
                              void* d_out, int out_size, void* d_ws, size_t ws_size,
                              hipStream_t stream) {
  const float* x = (const float*)d_in[0];
  const float* w = (const float*)d_in[1];
  const float* bias = (const float*)d_in[2];
  const float* kk = (const float*)d_in[3];
  const float* aa = (const float*)d_in[4];
  float* out = (float*)d_out;

  uint32_t* wb = (uint32_t*)d_ws;  // 2 MB bf16 w_bin
  wconv<<<(N_DIM * K_DIM) / (256 * 16), 256, 0, stream>>>(w, kk, aa, wb);

  const int M = in_sizes[0] / K_DIM;         // 32768
  const int grid = (M / BM) * (N_DIM / BN);  // 256 * 4 = 1024
  binlin_fused3c<<<grid, 512, 0, stream>>>(x, wb, bias, out);
}